// Round 10
// baseline (912.683 us; speedup 1.0000x reference)
//
#include <hip/hip_runtime.h>
#include <hip/hip_bf16.h>
#include <hip/hip_cooperative_groups.h>

namespace cg = cooperative_groups;

#define BB 8
#define FF 64
#define NPTS 100000
#define RES 32
#define R3 32768                 // 32^3
#define EPSV 1e-6f
#define SEGS (BB*R3)             // 262144
#define NPTS_TOT (BB*NPTS)       // 800000
#define NWIN (NPTS_TOT/64)       // 12500
#define NBLK 512
#define NTHR 256
#define NTILES_N 1563            // ceil(NPTS/64)

static constexpr size_t GRID_ELEMS = (size_t)BB * FF * R3;

__device__ __forceinline__ float bf16f(ushort u) {
    return __uint_as_float((unsigned)u << 16);
}
__device__ __forceinline__ ushort f2bf(float f) {
    __hip_bfloat16 h = __float2bfloat16(f);
    return *reinterpret_cast<ushort*>(&h);
}

struct Params {
    const float* features; const float* coords;
    float* sums; int* rad; int* counts; int* offsets; int* bsum; int* boff;
    unsigned* voxrank; int* rowvox; int* perm;
    ushort* featT; ushort* avgS;
    float* grid; float* normout;
};

// ---------------- prep phases ----------------
__device__ void d_zero(const Params& p) {
    int t = blockIdx.x * NTHR + threadIdx.x;
    if (t < 24) p.sums[t] = 0.f;
    else if (t < 32) p.rad[t - 24] = 0;
    for (int i = t; i < SEGS; i += NBLK * NTHR) p.counts[i] = 0;
}

__device__ void d_sums(const Params& p) {
    int bid = blockIdx.x;
    int b = bid >> 6, chunk = bid & 63;        // 64 blocks per batch
    const float* cb = p.coords + (size_t)b * 3 * NPTS;
    float sx = 0.f, sy = 0.f, sz = 0.f;
    for (int i = chunk * NTHR + threadIdx.x; i < NPTS; i += 64 * NTHR) {
        sx += cb[i]; sy += cb[NPTS + i]; sz += cb[2 * NPTS + i];
    }
    for (int o = 32; o; o >>= 1) {
        sx += __shfl_down(sx, o); sy += __shfl_down(sy, o); sz += __shfl_down(sz, o);
    }
    if ((threadIdx.x & 63) == 0) {
        atomicAdd(&p.sums[b * 3 + 0], sx);
        atomicAdd(&p.sums[b * 3 + 1], sy);
        atomicAdd(&p.sums[b * 3 + 2], sz);
    }
}

__device__ void d_radius(const Params& p) {
    int bid = blockIdx.x;
    int b = bid >> 6, chunk = bid & 63;
    const float* cb = p.coords + (size_t)b * 3 * NPTS;
    float mx = p.sums[b * 3 + 0] / (float)NPTS;
    float my = p.sums[b * 3 + 1] / (float)NPTS;
    float mz = p.sums[b * 3 + 2] / (float)NPTS;
    float mval = 0.f;
    for (int i = chunk * NTHR + threadIdx.x; i < NPTS; i += 64 * NTHR) {
        float x = cb[i] - mx, y = cb[NPTS + i] - my, z = cb[2 * NPTS + i] - mz;
        mval = fmaxf(mval, sqrtf(x * x + y * y + z * z));
    }
    for (int o = 32; o; o >>= 1) mval = fmaxf(mval, __shfl_down(mval, o));
    if ((threadIdx.x & 63) == 0) atomicMax(&p.rad[b], __float_as_int(mval)); // >=0: int order ok
}

__device__ void d_voxelize(const Params& p) {
    for (int g = blockIdx.x * NTHR + threadIdx.x; g < NPTS_TOT; g += NBLK * NTHR) {
        int b = g / NPTS, n = g - b * NPTS;
        const float* cb = p.coords + (size_t)b * 3 * NPTS;
        float mx = p.sums[b * 3 + 0] / (float)NPTS;
        float my = p.sums[b * 3 + 1] / (float)NPTS;
        float mz = p.sums[b * 3 + 2] / (float)NPTS;
        float r = __int_as_float(p.rad[b]);
        float d = 2.0f * r + EPSV;
        float x = (cb[n] - mx) / d + 0.5f;
        float y = (cb[NPTS + n] - my) / d + 0.5f;
        float z = (cb[2 * NPTS + n] - mz) / d + 0.5f;
        float nx = fminf(fmaxf(x * (float)RES, 0.0f), (float)(RES - 1));
        float ny = fminf(fmaxf(y * (float)RES, 0.0f), (float)(RES - 1));
        float nz = fminf(fmaxf(z * (float)RES, 0.0f), (float)(RES - 1));
        float* nb_ = p.normout + (size_t)b * 3 * NPTS;
        nb_[n] = nx; nb_[NPTS + n] = ny; nb_[2 * NPTS + n] = nz;
        int vx = (int)rintf(nx), vy = (int)rintf(ny), vz = (int)rintf(nz);
        int idx = (vx * RES + vy) * RES + vz;                 // 15 bits
        unsigned rank = (unsigned)atomicAdd(&p.counts[(b << 15) + idx], 1);
        p.voxrank[g] = (rank << 15) | (unsigned)idx;          // rank<=2^17-1, exact 32-bit fit
    }
}

// scan over SEGS=512*512: per-block 512-elem exclusive scan + block totals
__device__ void d_scan1(const Params& p, int* wt) {
    int bid = blockIdx.x, t = threadIdx.x;
    int base = bid * 512;
    int c0 = p.counts[base + 2 * t], c1 = p.counts[base + 2 * t + 1];
    int s = c0 + c1;
    int lane = t & 63, w = t >> 6;
    int v = s;
    for (int o = 1; o < 64; o <<= 1) { int u = __shfl_up(v, o); if (lane >= o) v += u; }
    if (lane == 63) wt[w] = v;
    __syncthreads();
    int wof = 0;
    for (int i = 0; i < w; ++i) wof += wt[i];
    int ex = wof + v - s;
    p.offsets[base + 2 * t] = ex;
    p.offsets[base + 2 * t + 1] = ex + c0;
    if (t == 255) p.bsum[bid] = wof + v;
    __syncthreads();
}

__device__ void d_scan2(const Params& p, int* wt) {
    if (blockIdx.x != 0) return;
    int t = threadIdx.x;
    int c0 = p.bsum[2 * t], c1 = p.bsum[2 * t + 1];
    int s = c0 + c1;
    int lane = t & 63, w = t >> 6;
    int v = s;
    for (int o = 1; o < 64; o <<= 1) { int u = __shfl_up(v, o); if (lane >= o) v += u; }
    if (lane == 63) wt[w] = v;
    __syncthreads();
    int wof = 0;
    for (int i = 0; i < w; ++i) wof += wt[i];
    int ex = wof + v - s;
    p.boff[2 * t] = ex;
    p.boff[2 * t + 1] = ex + c0;
    __syncthreads();
}

__device__ void d_fillperm(const Params& p) {
    for (int v = blockIdx.x * NTHR + threadIdx.x; v < SEGS; v += NBLK * NTHR) {
        int off = p.offsets[v] + p.boff[v >> 9];
        int cnt = p.counts[v];
        for (int i = 0; i < cnt; ++i) p.rowvox[off + i] = v;
    }
    for (int g = blockIdx.x * NTHR + threadIdx.x; g < NPTS_TOT; g += NBLK * NTHR) {
        unsigned vr = p.voxrank[g];
        int idx = (int)(vr & 32767u);
        int rank = (int)(vr >> 15);
        int b = g / NPTS;
        int bv = (b << 15) | idx;
        p.perm[p.offsets[bv] + p.boff[bv >> 9] + rank] = g;
    }
}

// ---------------- main phases ----------------
__device__ void d_transpose(const Params& p, float (*tileF)[65]) {
    int tid = threadIdx.x, lane = tid & 63, wid = tid >> 6;
    for (int job = blockIdx.x; job < BB * NTILES_N; job += NBLK) {
        int b = job / NTILES_N;
        int n0 = (job - b * NTILES_N) * 64;
        __syncthreads();
        for (int f = wid; f < 64; f += 4) {
            int n = n0 + lane;
            tileF[f][lane] = (n < NPTS) ? p.features[((size_t)b * FF + f) * NPTS + n] : 0.f;
        }
        __syncthreads();
        size_t g0 = (size_t)b * NPTS + n0;
        int half = lane >> 5;
        int f0 = (lane & 31) * 2;
#pragma unroll
        for (int k = 0; k < 8; ++k) {
            int q = wid * 16 + k * 2 + half;
            if (n0 + q < NPTS) {
                unsigned val = (unsigned)f2bf(tileF[f0][q]) |
                               ((unsigned)f2bf(tileF[f0 + 1][q]) << 16);
                ((unsigned*)(p.featT + ((g0 + q) << 6)))[lane & 31] = val;
            }
        }
    }
}

__device__ void d_gather(const Params& p, ushort (*tile)[4096]) {
    int wid = threadIdx.x >> 6, lane = threadIdx.x & 63;
    for (int w = blockIdx.x * 4 + wid; w < NWIN; w += NBLK * 4) {
        int r0 = w * 64;
        int pr = p.perm[r0 + lane];
        int myv = p.rowvox[r0 + lane];
        uint4 t[8];
        uint4* ldst = (uint4*)tile[wid];
#pragma unroll
        for (int j = 0; j < 8; ++j) {
            int row = j * 8 + (lane >> 3);
            int pi = __shfl(pr, row);
            t[j] = ((const uint4*)(p.featT + ((size_t)pi << 6)))[lane & 7];
        }
#pragma unroll
        for (int j = 0; j < 8; ++j) ldst[j * 64 + lane] = t[j];

        int prevv = __shfl_up(myv, 1);
        if (lane == 0) prevv = (r0 > 0) ? p.rowvox[r0 - 1] : -1;
        unsigned long long flags = __ballot(myv != prevv);

        while (flags) {
            int s = (int)__ffsll(flags) - 1;
            flags &= flags - 1;
            int bv = __shfl(myv, s);
            int cnt = flags ? ((int)__ffsll(flags) - 1 - s) : p.counts[bv];
            int inwin = min(cnt, 64 - s);
            float acc = 0.f;
            for (int i = 0; i < inwin; ++i) acc += bf16f(tile[wid][(s + i) * 64 + lane]);
            int done = inwin;
            int rbase = r0 + 64;
            while (done < cnt) {                       // window-final segment overhang
                int chunk = min(64, cnt - done);
                int pi_l = p.perm[min(rbase + lane, NPTS_TOT - 1)];
#pragma unroll
                for (int j = 0; j < 8; ++j) {
                    int row = j * 8 + (lane >> 3);
                    int pi = __shfl(pi_l, row);
                    t[j] = ((const uint4*)(p.featT + ((size_t)pi << 6)))[lane & 7];
                }
#pragma unroll
                for (int j = 0; j < 8; ++j) ldst[j * 64 + lane] = t[j];
                for (int i = 0; i < chunk; ++i) acc += bf16f(tile[wid][i * 64 + lane]);
                done += chunk;
                rbase += 64;
            }
            p.avgS[(size_t)bv * 64 + lane] = f2bf(acc / (float)cnt);
        }
    }
}

__device__ void d_avg2grid(const Params& p, float (*tile)[65]) {
    int lane = threadIdx.x & 63, wid = threadIdx.x >> 6;
    for (int job = blockIdx.x; job < SEGS / 64; job += NBLK) {
        int bv0 = job * 64;
        __syncthreads();
        for (int q = wid; q < 64; q += 4) {
            int cnt = p.counts[bv0 + q];
            tile[q][lane] = (cnt > 0) ? bf16f(p.avgS[(size_t)(bv0 + q) * 64 + lane]) : 0.f;
        }
        __syncthreads();
        int b = bv0 >> 15;
        int v0 = bv0 & (R3 - 1);
        for (int f = wid; f < 64; f += 4) {
            p.grid[((size_t)b * FF + f) * R3 + v0 + lane] = tile[lane][f];
        }
    }
}

// ---------------- cooperative fused kernels ----------------
__global__ __launch_bounds__(NTHR) void k_prep(Params p) {
    __shared__ int wt[4];
    cg::grid_group g = cg::this_grid();
    d_zero(p);        g.sync();
    d_sums(p);        g.sync();
    d_radius(p);      g.sync();
    d_voxelize(p);    g.sync();
    d_scan1(p, wt);   g.sync();
    d_scan2(p, wt);   g.sync();
    d_fillperm(p);
}

__global__ __launch_bounds__(NTHR) void k_main(Params p) {
    __shared__ union SM { float tf[64][65]; ushort tg[4][4096]; } sm;  // 32 KB
    cg::grid_group g = cg::this_grid();
    d_transpose(p, sm.tf);  g.sync();
    d_gather(p, sm.tg);     g.sync();
    d_avg2grid(p, sm.tf);
}

// ---------------- fallback wrappers (plain launches) ----------------
__global__ void w_zero(Params p) { d_zero(p); }
__global__ void w_sums(Params p) { d_sums(p); }
__global__ void w_radius(Params p) { d_radius(p); }
__global__ void w_voxelize(Params p) { d_voxelize(p); }
__global__ void w_scan1(Params p) { __shared__ int wt[4]; d_scan1(p, wt); }
__global__ void w_scan2(Params p) { __shared__ int wt[4]; d_scan2(p, wt); }
__global__ void w_fillperm(Params p) { d_fillperm(p); }
__global__ void w_transpose(Params p) { __shared__ float tf[64][65]; d_transpose(p, tf); }
__global__ void w_gather(Params p) { __shared__ ushort tg[4][4096]; d_gather(p, tg); }
__global__ void w_avg2grid(Params p) { __shared__ float tf[64][65]; d_avg2grid(p, tf); }

extern "C" void kernel_launch(void* const* d_in, const int* in_sizes, int n_in,
                              void* d_out, int out_size, void* d_ws, size_t ws_size,
                              hipStream_t stream) {
    const float* features = (const float*)d_in[0];
    const float* coords = (const float*)d_in[1];
    float* out = (float*)d_out;
    float* grid = out;                      // [B,F,R,R,R]
    float* norm_out = out + GRID_ELEMS;     // [B,3,N]

    char* ws = (char*)d_ws;
    size_t off_sums   = 0;                                    // 24 f
    size_t off_rad    = 128;                                  // 8 i
    size_t off_counts = 256;                                  // 1 MB
    size_t off_offs   = off_counts + (size_t)SEGS * 4;        // 1 MB
    size_t off_bsum   = off_offs + (size_t)SEGS * 4;          // 2 KB
    size_t off_boff   = off_bsum + 2048;                      // 2 KB
    size_t off_vrk    = off_boff + 2048;                      // 3.2 MB
    size_t off_rowv   = off_vrk + (size_t)NPTS_TOT * 4;       // 3.2 MB
    size_t off_perm   = off_rowv + (size_t)NPTS_TOT * 4;      // 3.2 MB
    size_t off_featT  = (off_perm + (size_t)NPTS_TOT * 4 + 255) & ~(size_t)255;  // 102.4 MB
    size_t off_avg    = (off_featT + (size_t)NPTS_TOT * FF * 2 + 255) & ~(size_t)255; // 33.5 MB

    Params pp;
    pp.features = features; pp.coords = coords;
    pp.sums = (float*)(ws + off_sums);
    pp.rad = (int*)(ws + off_rad);
    pp.counts = (int*)(ws + off_counts);
    pp.offsets = (int*)(ws + off_offs);
    pp.bsum = (int*)(ws + off_bsum);
    pp.boff = (int*)(ws + off_boff);
    pp.voxrank = (unsigned*)(ws + off_vrk);
    pp.rowvox = (int*)(ws + off_rowv);
    pp.perm = (int*)(ws + off_perm);
    pp.featT = (ushort*)(ws + off_featT);
    pp.avgS = (ushort*)(ws + off_avg);
    pp.grid = grid; pp.normout = norm_out;

    void* args[] = { (void*)&pp };
    hipError_t e = hipLaunchCooperativeKernel((const void*)k_prep, dim3(NBLK), dim3(NTHR),
                                              args, 0, stream);
    if (e == hipSuccess) {
        e = hipLaunchCooperativeKernel((const void*)k_main, dim3(NBLK), dim3(NTHR),
                                       args, 0, stream);
    }
    if (e != hipSuccess) {
        // fallback: same device code, plain sequential launches
        w_zero<<<NBLK, NTHR, 0, stream>>>(pp);
        w_sums<<<NBLK, NTHR, 0, stream>>>(pp);
        w_radius<<<NBLK, NTHR, 0, stream>>>(pp);
        w_voxelize<<<NBLK, NTHR, 0, stream>>>(pp);
        w_scan1<<<NBLK, NTHR, 0, stream>>>(pp);
        w_scan2<<<1, NTHR, 0, stream>>>(pp);
        w_fillperm<<<NBLK, NTHR, 0, stream>>>(pp);
        w_transpose<<<NBLK, NTHR, 0, stream>>>(pp);
        w_gather<<<NBLK, NTHR, 0, stream>>>(pp);
        w_avg2grid<<<NBLK, NTHR, 0, stream>>>(pp);
    }
}

// Round 11
// 860.475 us; speedup vs baseline: 1.0607x; 1.0607x over previous
//
#include <hip/hip_runtime.h>
#include <hip/hip_bf16.h>

#define BB 8
#define FF 64
#define NPTS 100000
#define RES 32
#define R3 32768                 // 32^3 = 1<<15
#define EPSV 1e-6f
#define SEGS (BB*R3)             // 262144
#define NPTS_TOT (BB*NPTS)       // 800000
#define NTILES_N 1563            // ceil(NPTS/64)
#define RNG_V 512                // voxels per accum block
#define NRNG (R3/RNG_V)          // 64 ranges per batch

static constexpr size_t GRID_ELEMS = (size_t)BB * FF * R3;

__device__ __forceinline__ float bf16f(ushort u) {
    return __uint_as_float((unsigned)u << 16);
}
__device__ __forceinline__ ushort f2bf(float f) {
    __hip_bfloat16 h = __float2bfloat16(f);
    return *reinterpret_cast<ushort*>(&h);
}

// ---------------- Kernel Z: fast zero (sums/rad/counts) ----------------
__global__ void k_zero(uint4* __restrict__ p, int n16) {
    int i = blockIdx.x * 256 + threadIdx.x;
    if (i < n16) p[i] = make_uint4(0u, 0u, 0u, 0u);
}

// ---------------- Kernel A: per-batch coordinate sums ----------------
#define NB_STAT 64
__global__ void k_sum_coords(const float* __restrict__ coords, float* __restrict__ sums) {
    int b = blockIdx.x / NB_STAT;
    int chunk = blockIdx.x % NB_STAT;
    const float* cb = coords + (size_t)b * 3 * NPTS;
    float sx = 0.f, sy = 0.f, sz = 0.f;
    for (int i = chunk * blockDim.x + threadIdx.x; i < NPTS; i += NB_STAT * blockDim.x) {
        sx += cb[i]; sy += cb[NPTS + i]; sz += cb[2 * NPTS + i];
    }
    for (int o = 32; o; o >>= 1) {
        sx += __shfl_down(sx, o); sy += __shfl_down(sy, o); sz += __shfl_down(sz, o);
    }
    if ((threadIdx.x & 63) == 0) {
        atomicAdd(&sums[b * 3 + 0], sx);
        atomicAdd(&sums[b * 3 + 1], sy);
        atomicAdd(&sums[b * 3 + 2], sz);
    }
}

// ---------------- Kernel B: per-batch max radius ----------------
__global__ void k_radius(const float* __restrict__ coords, const float* __restrict__ sums,
                         int* __restrict__ rad_bits) {
    int b = blockIdx.x / NB_STAT;
    int chunk = blockIdx.x % NB_STAT;
    const float* cb = coords + (size_t)b * 3 * NPTS;
    float mx = sums[b * 3 + 0] / (float)NPTS;
    float my = sums[b * 3 + 1] / (float)NPTS;
    float mz = sums[b * 3 + 2] / (float)NPTS;
    float mval = 0.f;
    for (int i = chunk * blockDim.x + threadIdx.x; i < NPTS; i += NB_STAT * blockDim.x) {
        float x = cb[i] - mx, y = cb[NPTS + i] - my, z = cb[2 * NPTS + i] - mz;
        mval = fmaxf(mval, sqrtf(x * x + y * y + z * z));
    }
    for (int o = 32; o; o >>= 1) mval = fmaxf(mval, __shfl_down(mval, o));
    if ((threadIdx.x & 63) == 0) atomicMax(&rad_bits[b], __float_as_int(mval)); // >=0: int order ok
}

// ---------------- Kernel C: per-point voxelize + norm_coords + counts ----------------
__global__ void k_voxelize(const float* __restrict__ coords, const float* __restrict__ sums,
                           const int* __restrict__ rad_bits, float* __restrict__ norm_out,
                           int* __restrict__ voxidx, int* __restrict__ counts) {
    int tid = blockIdx.x * blockDim.x + threadIdx.x;
    if (tid >= NPTS_TOT) return;
    int b = tid / NPTS, n = tid % NPTS;
    const float* cb = coords + (size_t)b * 3 * NPTS;
    float mx = sums[b * 3 + 0] / (float)NPTS;
    float my = sums[b * 3 + 1] / (float)NPTS;
    float mz = sums[b * 3 + 2] / (float)NPTS;
    float r = __int_as_float(rad_bits[b]);
    float d = 2.0f * r + EPSV;
    float x = (cb[n] - mx) / d + 0.5f;
    float y = (cb[NPTS + n] - my) / d + 0.5f;
    float z = (cb[2 * NPTS + n] - mz) / d + 0.5f;
    float nx = fminf(fmaxf(x * (float)RES, 0.0f), (float)(RES - 1));
    float ny = fminf(fmaxf(y * (float)RES, 0.0f), (float)(RES - 1));
    float nz = fminf(fmaxf(z * (float)RES, 0.0f), (float)(RES - 1));
    float* nb_ = norm_out + (size_t)b * 3 * NPTS;
    nb_[n] = nx; nb_[NPTS + n] = ny; nb_[2 * NPTS + n] = nz;
    int vx = (int)rintf(nx), vy = (int)rintf(ny), vz = (int)rintf(nz);
    int idx = (vx * RES + vy) * RES + vz;
    voxidx[tid] = idx;
    atomicAdd(&counts[(b << 15) + idx], 1);
}

// ---------------- Kernel D: transpose features[B,F,N] f32 -> featT[B*N][64] bf16 --------
__global__ void k_transpose(const float* __restrict__ features, ushort* __restrict__ featT) {
    __shared__ float tileF[64][65];
    int b = blockIdx.y;
    int n0 = blockIdx.x * 64;
    int tid = threadIdx.x, lane = tid & 63, wid = tid >> 6;
    for (int f = wid; f < 64; f += 4) {
        int n = n0 + lane;
        tileF[f][lane] = (n < NPTS) ? features[((size_t)b * FF + f) * NPTS + n] : 0.f;
    }
    __syncthreads();
    size_t g0 = (size_t)b * NPTS + n0;
    int half = lane >> 5;
    int f0 = (lane & 31) * 2;
#pragma unroll
    for (int k = 0; k < 8; ++k) {
        int p = wid * 16 + k * 2 + half;
        if (n0 + p < NPTS) {
            unsigned val = (unsigned)f2bf(tileF[f0][p]) | ((unsigned)f2bf(tileF[f0 + 1][p]) << 16);
            ((unsigned*)(featT + ((g0 + p) << 6)))[lane & 31] = val;
        }
    }
}

// ---------------- Kernel E: voxel-range-owner accumulate (no sort, no global atomics) ----
// Block = (batch b, 512-voxel range). Scans voxidx[b] (400 KB, XCD-L2-resident since
// b == bid%8), ballots in-range hits (~1.5%), and per hit all 64 lanes cooperatively
// load the point's 128 B featT row + one conflict-free LDS atomicAdd per lane into a
// 128 KB [v][f] slab (f XOR-rotated by v so hit-writes AND writeout are bank-clean).
// Writeout: fused count-divide, coalesced 2 KB runs per feature.
__global__ __launch_bounds__(1024) void k_accum2(const ushort* __restrict__ featT,
                                                 const int* __restrict__ voxidx,
                                                 const int* __restrict__ counts,
                                                 float* __restrict__ grid) {
    __shared__ float vox[RNG_V * 64];   // 128 KB, [v][(f+v)&63]
    int bid = blockIdx.x;               // [0, 512)
    int b = bid & 7;                    // = bid%8 -> all blocks of batch b on XCD b
    int rng = bid >> 3;
    int v0 = rng << 9;                  // range [v0, v0+512)

    for (int i = threadIdx.x; i < RNG_V * 64; i += 1024) vox[i] = 0.f;
    __syncthreads();

    int lane = threadIdx.x & 63;
    const int4* vrow = (const int4*)(voxidx + (size_t)b * NPTS);
    const ushort* frows = featT + ((size_t)b * NPTS << 6);
    const int NV = NPTS / 4;            // 25000
    const int NIT = (NV + 1023) / 1024; // 25

    for (int t = 0; t < NIT; ++t) {
        int i = t * 1024 + threadIdx.x;
        int4 v4 = (i < NV) ? vrow[i] : make_int4(-1, -1, -1, -1);
        int wbase = t * 1024 + (threadIdx.x & ~63);   // i of lane 0 in this wave
#pragma unroll
        for (int c = 0; c < 4; ++c) {
            int vc = (c == 0) ? v4.x : (c == 1) ? v4.y : (c == 2) ? v4.z : v4.w;
            int rel = vc - v0;
            unsigned long long m = __ballot((unsigned)rel < (unsigned)RNG_V);
            while (m) {
                int s = (int)__ffsll(m) - 1;
                m &= m - 1;
                int rel_s = __shfl(rel, s);
                size_t n = (size_t)(wbase + s) * 4 + c;
                float val = bf16f(frows[(n << 6) + lane]);          // 128B coalesced row
                atomicAdd(&vox[(rel_s << 6) + ((lane + rel_s) & 63)], val);  // 2-way bank: free
            }
        }
    }
    __syncthreads();

    const int* crow = counts + (b << 15) + v0;
    for (int idx = threadIdx.x; idx < RNG_V * 64; idx += 1024) {
        int f = idx >> 9, v = idx & (RNG_V - 1);       // consecutive lanes -> consecutive v
        int cnt = crow[v];
        float a = vox[(v << 6) + ((f + v) & 63)];      // banks (f+v)%32: conflict-free
        grid[(((size_t)(b * FF + f)) << 15) + v0 + v] = (cnt > 0) ? a / (float)cnt : 0.f;
    }
}

// ---------------- Fallback path (atomic scatter), used if ws too small ----------------
__global__ void k_scatter(const float* __restrict__ features, const int* __restrict__ voxidx,
                          float* __restrict__ grid) {
    size_t tid = (size_t)blockIdx.x * blockDim.x + threadIdx.x;
    if (tid >= (size_t)BB * FF * NPTS) return;
    int n = (int)(tid % NPTS);
    int bf = (int)(tid / NPTS);
    int b = bf >> 6;
    int idx = voxidx[(size_t)b * NPTS + n];
    atomicAdd(&grid[(size_t)bf * R3 + idx], features[tid]);
}

__global__ void k_normalize(float* __restrict__ grid, const int* __restrict__ counts) {
    size_t tid = (size_t)blockIdx.x * blockDim.x + threadIdx.x;
    if (tid >= GRID_ELEMS) return;
    int v = (int)(tid % R3);
    int bf = (int)(tid / R3);
    int b = bf >> 6;
    float c = (float)counts[b * R3 + v];
    grid[tid] = grid[tid] / fmaxf(c, 1.0f);
}

extern "C" void kernel_launch(void* const* d_in, const int* in_sizes, int n_in,
                              void* d_out, int out_size, void* d_ws, size_t ws_size,
                              hipStream_t stream) {
    const float* features = (const float*)d_in[0];
    const float* coords = (const float*)d_in[1];
    float* out = (float*)d_out;
    float* grid = out;                      // [B,F,R,R,R]
    float* norm_out = out + GRID_ELEMS;     // [B,3,N]

    char* ws = (char*)d_ws;
    size_t off_sums   = 0;                                    // 24 f
    size_t off_rad    = 128;                                  // 8 i
    size_t off_counts = 256;                                  // 1 MB
    size_t off_vox    = off_counts + (size_t)SEGS * 4;        // 3.2 MB
    size_t off_featT  = (off_vox + (size_t)NPTS_TOT * 4 + 255) & ~(size_t)255;  // 102.4 MB
    size_t needed     = off_featT + (size_t)NPTS_TOT * FF * 2;

    float* sums   = (float*)(ws + off_sums);
    int* rad_bits = (int*)(ws + off_rad);
    int* counts   = (int*)(ws + off_counts);
    int* voxidx   = (int*)(ws + off_vox);
    ushort* featT = (ushort*)(ws + off_featT);

    // zero sums/rad/counts (uint4 stores; in-graph hipMemsetAsync fill is pathological)
    int n16 = (int)((off_vox + 15) / 16);
    k_zero<<<(n16 + 255) / 256, 256, 0, stream>>>((uint4*)ws, n16);

    k_sum_coords<<<BB * NB_STAT, 256, 0, stream>>>(coords, sums);
    k_radius<<<BB * NB_STAT, 256, 0, stream>>>(coords, sums, rad_bits);

    int pts_blocks = (NPTS_TOT + 255) / 256;
    k_voxelize<<<pts_blocks, 256, 0, stream>>>(coords, sums, rad_bits, norm_out, voxidx, counts);

    if (ws_size >= needed) {
        dim3 tgrid(NTILES_N, BB);
        k_transpose<<<tgrid, 256, 0, stream>>>(features, featT);
        k_accum2<<<BB * NRNG, 1024, 0, stream>>>(featT, voxidx, counts, grid);
    } else {
        hipMemsetAsync(grid, 0, GRID_ELEMS * sizeof(float), stream);
        size_t st = (size_t)BB * FF * NPTS;
        k_scatter<<<(int)((st + 255) / 256), 256, 0, stream>>>(features, voxidx, grid);
        k_normalize<<<(int)((GRID_ELEMS + 255) / 256), 256, 0, stream>>>(grid, counts);
    }
}

// Round 12
// 294.436 us; speedup vs baseline: 3.0998x; 2.9225x over previous
//
#include <hip/hip_runtime.h>
#include <hip/hip_bf16.h>

#define BB 8
#define FF 64
#define NPTS 100000
#define RES 32
#define R3 32768                 // 1<<15
#define EPSV 1e-6f
#define SEGS (BB*R3)             // 262144
#define NPTS_TOT (BB*NPTS)       // 800000
#define NWIN (NPTS_TOT/64)       // 12500
#define NTILES_N 1563            // ceil(NPTS/64)

static constexpr size_t GRID_ELEMS = (size_t)BB * FF * R3;

__device__ __forceinline__ float bf16f(ushort u) {
    return __uint_as_float((unsigned)u << 16);
}
__device__ __forceinline__ ushort f2bf(float f) {
    __hip_bfloat16 h = __float2bfloat16(f);
    return *reinterpret_cast<ushort*>(&h);
}

// ---------------- zero sums+rad (tiny) ----------------
__global__ void k_zero0(float* __restrict__ sums, int* __restrict__ rad) {
    int t = threadIdx.x;
    if (t < 24) sums[t] = 0.f;
    else if (t < 32) rad[t - 24] = 0;
}

// ---------------- per-batch coordinate sums (+ zero counts slice) ----------------
__global__ void k_sums(const float* __restrict__ coords, float* __restrict__ sums,
                       int* __restrict__ counts) {
    int bid = blockIdx.x;                       // 512 blocks
    // zero my 512-int slice of counts (uint4)
    if (threadIdx.x < 128)
        ((uint4*)counts)[bid * 128 + threadIdx.x] = make_uint4(0u, 0u, 0u, 0u);

    int b = bid >> 6, chunk = bid & 63;         // 64 chunks per batch
    const float* cb = coords + (size_t)b * 3 * NPTS;
    float sx = 0.f, sy = 0.f, sz = 0.f;
    for (int i = chunk * 256 + threadIdx.x; i < NPTS; i += 64 * 256) {
        sx += cb[i]; sy += cb[NPTS + i]; sz += cb[2 * NPTS + i];
    }
    for (int o = 32; o; o >>= 1) {
        sx += __shfl_down(sx, o); sy += __shfl_down(sy, o); sz += __shfl_down(sz, o);
    }
    if ((threadIdx.x & 63) == 0) {
        atomicAdd(&sums[b * 3 + 0], sx);
        atomicAdd(&sums[b * 3 + 1], sy);
        atomicAdd(&sums[b * 3 + 2], sz);
    }
}

// ---------------- per-batch max radius ----------------
__global__ void k_radius(const float* __restrict__ coords, const float* __restrict__ sums,
                         int* __restrict__ rad) {
    int bid = blockIdx.x;
    int b = bid >> 6, chunk = bid & 63;
    const float* cb = coords + (size_t)b * 3 * NPTS;
    float mx = sums[b * 3 + 0] / (float)NPTS;
    float my = sums[b * 3 + 1] / (float)NPTS;
    float mz = sums[b * 3 + 2] / (float)NPTS;
    float mval = 0.f;
    for (int i = chunk * 256 + threadIdx.x; i < NPTS; i += 64 * 256) {
        float x = cb[i] - mx, y = cb[NPTS + i] - my, z = cb[2 * NPTS + i] - mz;
        mval = fmaxf(mval, sqrtf(x * x + y * y + z * z));
    }
    for (int o = 32; o; o >>= 1) mval = fmaxf(mval, __shfl_down(mval, o));
    if ((threadIdx.x & 63) == 0) atomicMax(&rad[b], __float_as_int(mval)); // >=0: int order ok
}

// ---------------- voxelize: norm_coords + packed (rank<<15|idx) ----------------
__global__ void k_voxelize(const float* __restrict__ coords, const float* __restrict__ sums,
                           const int* __restrict__ rad, float* __restrict__ norm_out,
                           unsigned* __restrict__ voxrank, int* __restrict__ counts) {
    int g = blockIdx.x * 256 + threadIdx.x;     // grid exact: 800000
    int b = g / NPTS, n = g - b * NPTS;
    const float* cb = coords + (size_t)b * 3 * NPTS;
    float mx = sums[b * 3 + 0] / (float)NPTS;
    float my = sums[b * 3 + 1] / (float)NPTS;
    float mz = sums[b * 3 + 2] / (float)NPTS;
    float r = __int_as_float(rad[b]);
    float d = 2.0f * r + EPSV;
    float x = (cb[n] - mx) / d + 0.5f;
    float y = (cb[NPTS + n] - my) / d + 0.5f;
    float z = (cb[2 * NPTS + n] - mz) / d + 0.5f;
    float nx = fminf(fmaxf(x * (float)RES, 0.0f), (float)(RES - 1));
    float ny = fminf(fmaxf(y * (float)RES, 0.0f), (float)(RES - 1));
    float nz = fminf(fmaxf(z * (float)RES, 0.0f), (float)(RES - 1));
    float* nb_ = norm_out + (size_t)b * 3 * NPTS;
    nb_[n] = nx; nb_[NPTS + n] = ny; nb_[2 * NPTS + n] = nz;
    int vx = (int)rintf(nx), vy = (int)rintf(ny), vz = (int)rintf(nz);
    int idx = (vx * RES + vy) * RES + vz;       // 15 bits
    unsigned rank = (unsigned)atomicAdd(&counts[(b << 15) + idx], 1);
    voxrank[g] = (rank << 15) | (unsigned)idx;  // rank < 2^17: exact fit
}

// ---------------- scan: 512 blocks x 512 elems ----------------
__global__ void k_scan1(const int* __restrict__ counts, int* __restrict__ offsets,
                        int* __restrict__ bsum) {
    __shared__ int wt[4];
    int bid = blockIdx.x, t = threadIdx.x;
    int base = bid * 512;
    int c0 = counts[base + 2 * t], c1 = counts[base + 2 * t + 1];
    int s = c0 + c1;
    int lane = t & 63, w = t >> 6;
    int v = s;
    for (int o = 1; o < 64; o <<= 1) { int u = __shfl_up(v, o); if (lane >= o) v += u; }
    if (lane == 63) wt[w] = v;
    __syncthreads();
    int wof = 0;
    for (int i = 0; i < w; ++i) wof += wt[i];
    int ex = wof + v - s;
    offsets[base + 2 * t] = ex;
    offsets[base + 2 * t + 1] = ex + c0;
    if (t == 255) bsum[bid] = wof + v;
}

__global__ void k_scan2(const int* __restrict__ bsum, int* __restrict__ boff) {
    __shared__ int wt[4];
    int t = threadIdx.x;
    int c0 = bsum[2 * t], c1 = bsum[2 * t + 1];
    int s = c0 + c1;
    int lane = t & 63, w = t >> 6;
    int v = s;
    for (int o = 1; o < 64; o <<= 1) { int u = __shfl_up(v, o); if (lane >= o) v += u; }
    if (lane == 63) wt[w] = v;
    __syncthreads();
    int wof = 0;
    for (int i = 0; i < w; ++i) wof += wt[i];
    int ex = wof + v - s;
    boff[2 * t] = ex;
    boff[2 * t + 1] = ex + c0;
}

// ---------------- perm scatter: perm[dst]=g, rowvox[dst]=bv ----------------
__global__ void k_perm(const unsigned* __restrict__ voxrank, const int* __restrict__ offsets,
                       const int* __restrict__ boff, int* __restrict__ perm,
                       int* __restrict__ rowvox) {
    int g = blockIdx.x * 256 + threadIdx.x;     // exact 800000
    unsigned vr = voxrank[g];
    int idx = (int)(vr & 32767u);
    int rank = (int)(vr >> 15);
    int b = g / NPTS;
    int bv = (b << 15) | idx;
    int dst = offsets[bv] + boff[bv >> 9] + rank;
    perm[dst] = g;
    rowvox[dst] = bv;
}

// ---------------- transpose features[B,F,N] f32 -> featT[B*N][64] bf16 ----------------
__global__ void k_transpose(const float* __restrict__ features, ushort* __restrict__ featT) {
    __shared__ float tileF[64][65];
    int b = blockIdx.y;
    int n0 = blockIdx.x * 64;
    int tid = threadIdx.x, lane = tid & 63, wid = tid >> 6;

    // load: float4 over n (16B/lane), 16 rows per pass x 4 passes
    int ng = tid & 15, fr = tid >> 4;
    for (int fo = 0; fo < 64; fo += 16) {
        int f = fo + fr;
        int n = n0 + ng * 4;
        float4 v = make_float4(0.f, 0.f, 0.f, 0.f);
        if (n < NPTS) v = *(const float4*)&features[((size_t)b * FF + f) * NPTS + n];
        tileF[f][ng * 4 + 0] = v.x;
        tileF[f][ng * 4 + 1] = v.y;
        tileF[f][ng * 4 + 2] = v.z;
        tileF[f][ng * 4 + 3] = v.w;
    }
    __syncthreads();
    size_t g0 = (size_t)b * NPTS + n0;
    int half = lane >> 5;
    int f0 = (lane & 31) * 2;
#pragma unroll
    for (int k = 0; k < 8; ++k) {
        int p = wid * 16 + k * 2 + half;
        if (n0 + p < NPTS) {
            unsigned val = (unsigned)f2bf(tileF[f0][p]) | ((unsigned)f2bf(tileF[f0 + 1][p]) << 16);
            ((unsigned*)(featT + ((g0 + p) << 6)))[lane & 31] = val;   // 256B/instr
        }
    }
}

// ---------------- linear segmented gather (perm-indirect, chunked overhang) ----------
__global__ void k_gather(const ushort* __restrict__ featT, const int* __restrict__ perm,
                         const int* __restrict__ rowvox, const int* __restrict__ counts,
                         ushort* __restrict__ avgS) {
    __shared__ ushort tile[4][4096];   // 8KB per wave
    int wid = threadIdx.x >> 6, lane = threadIdx.x & 63;
    int w = blockIdx.x * 4 + wid;      // [0, NWIN)
    int r0 = w * 64;

    int pr = perm[r0 + lane];
    int myv = rowvox[r0 + lane];

    uint4 t[8];
    uint4* ldst = (uint4*)tile[wid];
#pragma unroll
    for (int j = 0; j < 8; ++j) {
        int row = j * 8 + (lane >> 3);
        int pi = __shfl(pr, row);
        t[j] = ((const uint4*)(featT + ((size_t)pi << 6)))[lane & 7];
    }
#pragma unroll
    for (int j = 0; j < 8; ++j) ldst[j * 64 + lane] = t[j];

    int prevv = __shfl_up(myv, 1);
    if (lane == 0) prevv = (r0 > 0) ? rowvox[r0 - 1] : -1;
    unsigned long long flags = __ballot(myv != prevv);

    while (flags) {
        int s = (int)__ffsll(flags) - 1;
        flags &= flags - 1;
        int bv = __shfl(myv, s);
        int cnt = flags ? ((int)__ffsll(flags) - 1 - s) : counts[bv];
        int inwin = min(cnt, 64 - s);
        float acc = 0.f;
        for (int i = 0; i < inwin; ++i) acc += bf16f(tile[wid][(s + i) * 64 + lane]);
        int done = inwin;
        int rbase = r0 + 64;
        while (done < cnt) {               // window-final segment: tile reusable
            int chunk = min(64, cnt - done);
            int pi_l = perm[min(rbase + lane, NPTS_TOT - 1)];
#pragma unroll
            for (int j = 0; j < 8; ++j) {
                int row = j * 8 + (lane >> 3);
                int pi = __shfl(pi_l, row);
                t[j] = ((const uint4*)(featT + ((size_t)pi << 6)))[lane & 7];
            }
#pragma unroll
            for (int j = 0; j < 8; ++j) ldst[j * 64 + lane] = t[j];
            for (int i = 0; i < chunk; ++i) acc += bf16f(tile[wid][i * 64 + lane]);
            done += chunk;
            rbase += 64;
        }
        avgS[(size_t)bv * 64 + lane] = f2bf(acc / (float)cnt);
    }
}

// ---------------- avgS [BV][F] bf16 -> grid [B][F][V] f32 ----------------
__global__ void k_avg2grid(const ushort* __restrict__ avgS, const int* __restrict__ counts,
                           float* __restrict__ grid) {
    __shared__ float tile[64][65];
    int bv0 = blockIdx.x * 64;
    int lane = threadIdx.x & 63, wid = threadIdx.x >> 6;
    for (int p = wid; p < 64; p += 4) {
        int cnt = counts[bv0 + p];
        tile[p][lane] = (cnt > 0) ? bf16f(avgS[(size_t)(bv0 + p) * 64 + lane]) : 0.f;
    }
    __syncthreads();
    int b = bv0 >> 15;
    int v0 = bv0 & (R3 - 1);
    for (int f = wid; f < 64; f += 4) {
        grid[((size_t)b * FF + f) * R3 + v0 + lane] = tile[lane][f];
    }
}

// ---------------- fallback (ws too small): atomic scatter ----------------
__global__ void k_scatter(const float* __restrict__ features, const unsigned* __restrict__ voxrank,
                          float* __restrict__ grid) {
    size_t tid = (size_t)blockIdx.x * blockDim.x + threadIdx.x;
    if (tid >= (size_t)BB * FF * NPTS) return;
    int n = (int)(tid % NPTS);
    int bf = (int)(tid / NPTS);
    int b = bf >> 6;
    int idx = (int)(voxrank[(size_t)b * NPTS + n] & 32767u);
    atomicAdd(&grid[(size_t)bf * R3 + idx], features[tid]);
}

__global__ void k_normalize(float* __restrict__ grid, const int* __restrict__ counts) {
    size_t tid = (size_t)blockIdx.x * blockDim.x + threadIdx.x;
    if (tid >= GRID_ELEMS) return;
    int v = (int)(tid % R3);
    int bf = (int)(tid / R3);
    int b = bf >> 6;
    float c = (float)counts[b * R3 + v];
    grid[tid] = grid[tid] / fmaxf(c, 1.0f);
}

extern "C" void kernel_launch(void* const* d_in, const int* in_sizes, int n_in,
                              void* d_out, int out_size, void* d_ws, size_t ws_size,
                              hipStream_t stream) {
    const float* features = (const float*)d_in[0];
    const float* coords = (const float*)d_in[1];
    float* out = (float*)d_out;
    float* grid = out;                      // [B,F,R,R,R]
    float* norm_out = out + GRID_ELEMS;     // [B,3,N]

    char* ws = (char*)d_ws;
    size_t off_sums  = 0;                                     // 24 f
    size_t off_rad   = 128;                                   // 8 i
    size_t off_cnt   = 256;                                   // 1 MB
    size_t off_offs  = off_cnt + (size_t)SEGS * 4;            // 1 MB
    size_t off_bsum  = off_offs + (size_t)SEGS * 4;           // 2 KB
    size_t off_boff  = off_bsum + 2048;                       // 2 KB
    size_t off_vrk   = off_boff + 2048;                       // 3.2 MB
    size_t off_rowv  = off_vrk + (size_t)NPTS_TOT * 4;        // 3.2 MB
    size_t off_perm  = off_rowv + (size_t)NPTS_TOT * 4;       // 3.2 MB
    size_t off_featT = (off_perm + (size_t)NPTS_TOT * 4 + 255) & ~(size_t)255;  // 102.4 MB
    size_t off_avg   = (off_featT + (size_t)NPTS_TOT * FF * 2 + 255) & ~(size_t)255; // 33.5 MB
    size_t needed    = off_avg + (size_t)SEGS * FF * 2;

    float* sums    = (float*)(ws + off_sums);
    int* rad       = (int*)(ws + off_rad);
    int* counts    = (int*)(ws + off_cnt);
    int* offsets   = (int*)(ws + off_offs);
    int* bsum      = (int*)(ws + off_bsum);
    int* boff      = (int*)(ws + off_boff);
    unsigned* vrk  = (unsigned*)(ws + off_vrk);
    int* rowvox    = (int*)(ws + off_rowv);
    int* perm      = (int*)(ws + off_perm);
    ushort* featT  = (ushort*)(ws + off_featT);
    ushort* avgS   = (ushort*)(ws + off_avg);

    k_zero0<<<1, 64, 0, stream>>>(sums, rad);
    k_sums<<<512, 256, 0, stream>>>(coords, sums, counts);     // also zeros counts
    k_radius<<<512, 256, 0, stream>>>(coords, sums, rad);
    k_voxelize<<<NPTS_TOT / 256, 256, 0, stream>>>(coords, sums, rad, norm_out, vrk, counts);

    if (ws_size >= needed) {
        k_scan1<<<512, 256, 0, stream>>>(counts, offsets, bsum);
        k_scan2<<<1, 256, 0, stream>>>(bsum, boff);
        k_perm<<<NPTS_TOT / 256, 256, 0, stream>>>(vrk, offsets, boff, perm, rowvox);
        dim3 tgrid(NTILES_N, BB);
        k_transpose<<<tgrid, 256, 0, stream>>>(features, featT);
        k_gather<<<NWIN / 4, 256, 0, stream>>>(featT, perm, rowvox, counts, avgS);
        k_avg2grid<<<SEGS / 64, 256, 0, stream>>>(avgS, counts, grid);
    } else {
        hipMemsetAsync(grid, 0, GRID_ELEMS * sizeof(float), stream);
        size_t st = (size_t)BB * FF * NPTS;
        k_scatter<<<(int)((st + 255) / 256), 256, 0, stream>>>(features, vrk, grid);
        k_normalize<<<(int)((GRID_ELEMS + 255) / 256), 256, 0, stream>>>(grid, counts);
    }
}